// Round 9
// baseline (126.467 us; speedup 1.0000x reference)
//
#include <hip/hip_runtime.h>

// RSI replicating jax-CPU cumsum via XLA ReduceWindowRewriter(base_length=16):
//   pad e[0..NP) with trailing zeros to 8192; reshape [512,16]
//   level-0: each 16-tile scanned SEQUENTIALLY; tile sums (512) -> recursively
//   [32,16] -> (32) -> [2,16] -> (2) -> len-2 scan; unwind adds ONE RN
//   exclusive outer offset per level.
//
// R1: LDS tile stride 16 -> 17 (bank conflicts 2.07e7 -> 2.33e6).
// R2: level-0 scan in regs; epilogue rcp-based. 66us/disp.
// R3/R4: register cumsum, 1 tile/thread; store scatter kept it ~98us.
// R5: outputs staged through padded LDS -> coalesced stores. ~38us.
// R6: coalesced load staging + LDS lifetime aliasing (SH). ~37us.
// R7: 4 blocks/CU (launch_bounds(512,8), 40.4KB LDS) + merged B1/B2 on
//     wave 0 with intra-wave lgkmcnt drain. ~34.7us.
// R8: LDS/VMEM instruction-issue cuts (no arithmetic change):
//   (a) BP rows padded to 16 floats, 16B-aligned: lane-63 export = 8x
//       ds_write_b128 (was 26 b32); lane-0 import = 8x ds_read_b128 at
//       k=0,4,8,12 (was 26 exec-masked b32 issued per wave inside the
//       k-loop), per-k select via cndmask (VALU) instead of LDS.
//       Phase-D LDS issue ~68 -> ~50 instr/wave; phase-C 26 -> 8.
//   (b) phase E: float4 global stores with per-row alignment peel
//       (row*8179 mod 4 varies; peel s head scalars then dwordx4).
//       Global store instr 16 -> ~4 per thread.
//   Output bit-identical: pure data-movement changes.
// R9 == R8 resubmitted: round-8 bench died on container acquisition
//   ("MI355X container failed twice") before running anything; source
//   re-audited (LDS 40592B <= 40960 for 4 blocks/CU; phase-E alignment
//   and tail coverage exact; no dynamic register indexing) -- unchanged.

constexpr int ROWS = 2048;
constexpr int COLS = 8192;
constexpr int NP   = COLS - 1;   // 8191 p-values; padded to 8192
constexpr int BT   = 256;        // fallback block size
constexpr int BT8  = 512;        // one 16-tile per thread
constexpr int TS   = 17;         // padded tile stride (16 data + 1 pad)

__device__ __forceinline__ int sidx(int f) {   // stage pad: +4 floats per 64
    return f + ((f >> 6) << 2);
}

__device__ __forceinline__ float f4c(const float4& v, int c) {  // static c
    return c == 0 ? v.x : c == 1 ? v.y : c == 2 ? v.z : v.w;
}

// ---------------------------------------------------------------- R8 kernel
template<int WM1>
__global__ __launch_bounds__(BT8, 8)
void rsi_reg_kernel(const float* __restrict__ x,
                    float* __restrict__ out,
                    int outW)
{
    static_assert(WM1 >= 1 && WM1 <= 16, "phase-D mapping needs WM1<=16");
    // Multi-lifetime buffer:
    //   A0..A : staged input row, addr sidx(f), max 8191+508=8699
    //   B..C  : S1g = SH[0..544), S1l = SH[544..1088)  (raw level-1 scan)
    //   D..E  : XBUF, addr o + (o>>4), max 8178+511=8689
    __shared__ float SH[8704];
    __shared__ float T0g[544], T0l[544];   // level-0 tile sums (padded idx)
    __shared__ float T1g[32],  T1l[32];    // level-1 tile sums
    __shared__ float S2g[32],  S2l[32];    // level-2 scan values (raw)
    __shared__ float T2g[2],   T2l[2];     // level-2 tile sums (T2g[0]==S3g[0])
    // wave-boundary prev-tile cs[16-WM1..15]: slot w holds tile 64w+63.
    // Rows padded to 16 floats + 16B-aligned for b128 export/import.
    __shared__ __align__(16) float BPg[7][16], BPl[7][16];

    float* const S1g = SH;                 // aliased lifetimes (see above)
    float* const S1l = SH + 544;

    const int row  = blockIdx.x;
    const int t    = threadIdx.x;          // == tile index b, 0..511
    const int lane = t & 63;
    const int w    = t >> 6;               // wave id 0..7
    const float* __restrict__ xr = x + (size_t)row * COLS;

    float rg[16], rl[16];                  // level-0 scan -> final cumsum

    // ---- phase A0: stage row into LDS, ideally coalesced
    #pragma unroll
    for (int m = 0; m < 4; ++m) {
        const int f = 4 * (t + 512 * m);   // f%4==0; f..f+3 in one 64-group
        const float4 v = *reinterpret_cast<const float4*>(xr + f);
        *reinterpret_cast<float4*>(&SH[sidx(f)]) = v;
    }
    __syncthreads();

    // ---- phase A: elements + level-0 sequential 16-tile scan (regs only)
    {
        float xe[17];
        {
            const int base = sidx(16 * t); // 16t..16t+15 share one 64-group
            #pragma unroll
            for (int q = 0; q < 4; ++q) {
                const float4 v = *reinterpret_cast<const float4*>(&SH[base + 4 * q]);
                xe[4*q+0]=v.x; xe[4*q+1]=v.y; xe[4*q+2]=v.z; xe[4*q+3]=v.w;
            }
            xe[16] = (t < 511) ? SH[sidx(16 * t + 16)] : 0.f; // unused j==NP
        }

        float cg = 0.f, cl = 0.f;
        #pragma unroll
        for (int r = 0; r < 16; ++r) {
            const int j = 16 * t + r;
            float eg = 0.f, el = 0.f;
            if (j < NP) {
                const float prev = xe[r];
                const float nxt  = xe[r + 1];
                if (prev != 0.f) {
                    const float p = (nxt - prev) / prev;   // IEEE f32 div (exact)
                    eg = (p > 0.f) ?  p : 0.f;
                    el = (p < 0.f) ? -p : 0.f;
                }
            }
            cg = cg + eg;          // RN; trailing pad adds +0 (bit-neutral)
            cl = cl + el;
            rg[r] = cg;
            rl[r] = cl;
        }
        T0g[t + (t >> 4)] = cg;    // padded T0 index
        T0l[t + (t >> 4)] = cl;
    }
    __syncthreads();               // staged input dead; SH becomes S1

    // ---- phase B (merged B1+B2, wave 0 only):
    //   B1: 64 independent chains (32 tiles x {g,l}), one per lane.
    //   B2: 4 independent chains (2 level-2 tiles x {g,l}) on lanes 0..3,
    //       after an intra-wave lgkmcnt(0) drain.
    if (t < 64) {
        const int  tt  = t & 31;
        const bool isl = (t >= 32);
        const float* __restrict__ src  = isl ? T0l : T0g;
        float* __restrict__       dstS = isl ? S1l : S1g;
        float* __restrict__       dstT = isl ? T1l : T1g;
        float v[16];
        #pragma unroll
        for (int s = 0; s < 16; ++s) v[s] = src[TS * tt + s];
        float c = 0.f;
        #pragma unroll
        for (int s = 0; s < 16; ++s) {
            c = c + v[s];                      // sequential RN chain (exact)
            dstS[TS * tt + s] = c;             // RAW scan value
        }
        dstT[tt] = c;

        asm volatile("s_waitcnt lgkmcnt(0)" ::: "memory");  // T1 visible in-wave

        if (t < 4) {                           // lanes 0..3: (g/l) x tile d
            const int  d    = t & 1;           // level-2 tile 0/1
            const bool isl2 = (t >= 2);
            const float* __restrict__ srcT = isl2 ? T1l : T1g;
            float* __restrict__       dstS2 = isl2 ? S2l : S2g;
            float* __restrict__       dstT2 = isl2 ? T2l : T2g;
            float u[16];
            #pragma unroll
            for (int q = 0; q < 16; ++q) u[q] = srcT[16 * d + q];
            float c2 = 0.f;
            #pragma unroll
            for (int q = 0; q < 16; ++q) {
                c2 = c2 + u[q];                // sequential RN chain (exact)
                dstS2[16 * d + q] = c2;        // raw scan values
            }
            dstT2[d] = c2;                     // T2g[0] == old S3g[0]
        }
    }
    __syncthreads();

    // ---- phase C: finalize cumsum IN REGISTERS.
    //      og = RN(S1raw[t-1] + RN(S2raw[c-1] (+ T2g[0] if c-1>=16)))
    //      == the old separate S2-finalize + S1-finalize RN sequence.
    //      Then rg += og (single RN add; t==0 adds +0.0, bit-neutral).
    {
        float og = 0.f, ol = 0.f;
        if (t >= 1) {
            const int bp = (t - 1) + ((t - 1) >> 4);
            og = S1g[bp]; ol = S1l[bp];        // raw level-1 scan
            const int c = (t - 1) >> 4;
            if (c >= 1) {
                float o2g = S2g[c - 1], o2l = S2l[c - 1];
                if (c - 1 >= 16) {             // level-3 offset (== S3g[0])
                    o2g = o2g + T2g[0];
                    o2l = o2l + T2l[0];
                }
                og = og + o2g;                 // RN(S1raw + finalizedS2)
                ol = ol + o2l;
            }
        }
        #pragma unroll
        for (int r = 0; r < 16; ++r) {
            rg[r] = rg[r] + og;
            rl[r] = rl[r] + ol;
        }
    }
    // boundary export: lane 63 of wave w publishes its tile tail for wave
    // w+1, packed as 4x float4 (BP[w][q] = cs tail value q = rg[q+16-WM1])
    if (lane == 63 && w < 7) {
        float4 g0{rg[3], rg[4], rg[5], rg[6]};
        float4 g1{rg[7], rg[8], rg[9], rg[10]};
        float4 g2{rg[11], rg[12], rg[13], rg[14]};
        float4 g3{rg[15], 0.f, 0.f, 0.f};
        *reinterpret_cast<float4*>(&BPg[w][0])  = g0;
        *reinterpret_cast<float4*>(&BPg[w][4])  = g1;
        *reinterpret_cast<float4*>(&BPg[w][8])  = g2;
        *reinterpret_cast<float4*>(&BPg[w][12]) = g3;
        float4 l0{rl[3], rl[4], rl[5], rl[6]};
        float4 l1{rl[7], rl[8], rl[9], rl[10]};
        float4 l2{rl[11], rl[12], rl[13], rl[14]};
        float4 l3{rl[15], 0.f, 0.f, 0.f};
        *reinterpret_cast<float4*>(&BPl[w][0])  = l0;
        *reinterpret_cast<float4*>(&BPl[w][4])  = l1;
        *reinterpret_cast<float4*>(&BPl[w][8])  = l2;
        *reinterpret_cast<float4*>(&BPl[w][12]) = l3;
    }
    __syncthreads();               // S1 dead; SH becomes XBUF

    // ---- phase D: compute 16 outputs, stage into SH (padded, 2-way banks)
    //      o = 16t-(WM1-1)+k; cs[o+WM1-1]=rg[k]; cs[o-1]=rg[k-WM1] (k>=WM1)
    //      or prev-tile tail: shfl_up(1), lane 0 overridden from BP quads
    //      (b128 loads at k=0,4,8,12; per-k select is VALU cndmask).
    {
        const bool use_bp = (lane == 0 && w > 0);
        float4 bg = {0.f, 0.f, 0.f, 0.f}, bl = {0.f, 0.f, 0.f, 0.f};
        const int o0 = 16 * t - (WM1 - 1);
        #pragma unroll
        for (int k = 0; k < 16; ++k) {
            const int o = o0 + k;
            float cg1, cl1;
            if (k >= WM1) {
                cg1 = rg[k - WM1]; cl1 = rl[k - WM1];
            } else {
                if ((k & 3) == 0) {
                    if (use_bp) {
                        bg = *reinterpret_cast<const float4*>(&BPg[w - 1][k]);
                        bl = *reinterpret_cast<const float4*>(&BPl[w - 1][k]);
                    }
                }
                const float sg = __shfl_up(rg[k + 16 - WM1], 1);
                const float sl = __shfl_up(rl[k + 16 - WM1], 1);
                cg1 = use_bp ? f4c(bg, k & 3) : sg;   // k&3 is compile-time
                cl1 = use_bp ? f4c(bl, k & 3) : sl;
            }
            if (o < 1) { cg1 = 0.f; cl1 = 0.f; }   // o==0 uses zero prefix
            const float a  = rg[k] - cg1;
            const float bb = rl[k] - cl1;
            float rs = 0.f;
            if (bb != 0.f) rs = a * __builtin_amdgcn_rcpf(bb);
            const float v = 1.f - __builtin_amdgcn_rcpf(1.f + rs);
            if ((unsigned)o < (unsigned)outW) SH[o + (o >> 4)] = v;
        }
    }
    __syncthreads();

    // ---- phase E: coalesced vectorized store.
    //      Global row base out+row*outW has (row*outW)%4 in {0..3}; peel s
    //      leading scalars so dwordx4 stores are 16B-aligned.
    {
        float* __restrict__ outr = out + (size_t)row * outW;
        const int s  = (4 - ((row * outW) & 3)) & 3;   // head scalars
        const int Nv = (outW - s) >> 2;                // float4 chunks
        for (int i = t; i < Nv; i += BT8) {
            const int o = s + 4 * i;
            float4 v;
            v.x = SH[(o    ) + ((o    ) >> 4)];
            v.y = SH[(o + 1) + ((o + 1) >> 4)];
            v.z = SH[(o + 2) + ((o + 2) >> 4)];
            v.w = SH[(o + 3) + ((o + 3) >> 4)];
            *reinterpret_cast<float4*>(outr + o) = v;
        }
        if (t < s) {                                   // head: o = t < s
            outr[t] = SH[t + (t >> 4)];
        } else if (t >= 4) {
            const int tail0 = s + 4 * Nv;
            const int q = t - 4;                       // tail: 0..(outW-tail0)
            if (q < outW - tail0) {
                const int o = tail0 + q;
                outr[o] = SH[o + (o >> 4)];
            }
        }
    }
}

// ------------------------------------------------- generic fallback (== R2)
__global__ __launch_bounds__(BT, 1)
void rsi_rwr_fallback(const float* __restrict__ x,
                      const int* __restrict__ wsp,
                      float* __restrict__ out,
                      int outW)
{
    __shared__ float CG[512 * TS], CL[512 * TS];
    __shared__ float T0g[544], T0l[544];
    __shared__ float S1g[544], S1l[544];
    __shared__ float T1g[32],  T1l[32];
    __shared__ float S2g[32],  S2l[32];
    __shared__ float T2g[2],   T2l[2];
    __shared__ float S3g[2],   S3l[2];

    const int row = blockIdx.x;
    const int t   = threadIdx.x;
    const int wm1 = *wsp - 1;
    const float* __restrict__ xr = x + (size_t)row * COLS;

    float rg[2][16], rl[2][16];

    #pragma unroll
    for (int bi = 0; bi < 2; ++bi) {
        const int b = t + 256 * bi;
        const float4* xv = reinterpret_cast<const float4*>(xr + 16 * b);
        float xe[17];
        {
            float4 v0 = xv[0], v1 = xv[1], v2 = xv[2], v3 = xv[3];
            xe[0]=v0.x;  xe[1]=v0.y;  xe[2]=v0.z;  xe[3]=v0.w;
            xe[4]=v1.x;  xe[5]=v1.y;  xe[6]=v1.z;  xe[7]=v1.w;
            xe[8]=v2.x;  xe[9]=v2.y;  xe[10]=v2.z; xe[11]=v2.w;
            xe[12]=v3.x; xe[13]=v3.y; xe[14]=v3.z; xe[15]=v3.w;
        }
        xe[16] = (b < 511) ? xr[16 * b + 16] : 0.f;

        float cg = 0.f, cl = 0.f;
        #pragma unroll
        for (int r = 0; r < 16; ++r) {
            const int j = 16 * b + r;
            float eg = 0.f, el = 0.f;
            if (j < NP) {
                const float prev = xe[r];
                const float nxt  = xe[r + 1];
                if (prev != 0.f) {
                    const float p = (nxt - prev) / prev;
                    eg = (p > 0.f) ?  p : 0.f;
                    el = (p < 0.f) ? -p : 0.f;
                }
            }
            cg = cg + eg;
            cl = cl + el;
            rg[bi][r] = cg;
            rl[bi][r] = cl;
        }
        T0g[b + (b >> 4)] = cg;
        T0l[b + (b >> 4)] = cl;
    }
    __syncthreads();

    if (t < 32) {
        float cg = 0.f, cl = 0.f;
        for (int s = 0; s < 16; ++s) {
            const int k = TS * t + s;
            cg = cg + T0g[k];
            cl = cl + T0l[k];
            S1g[k] = cg;
            S1l[k] = cl;
        }
        T1g[t] = cg; T1l[t] = cl;
    }
    __syncthreads();

    if (t < 2) {
        float cg = 0.f, cl = 0.f;
        for (int u = 0; u < 16; ++u) {
            cg = cg + T1g[16 * t + u];
            cl = cl + T1l[16 * t + u];
            S2g[16 * t + u] = cg;
            S2l[16 * t + u] = cl;
        }
        T2g[t] = cg; T2l[t] = cl;
    }
    __syncthreads();

    if (t == 0) {
        S3g[0] = T2g[0]; S3g[1] = T2g[0] + T2g[1];
        S3l[0] = T2l[0]; S3l[1] = T2l[0] + T2l[1];
    }
    __syncthreads();
    if (t >= 16 && t < 32) {
        S2g[t] = S2g[t] + S3g[0];
        S2l[t] = S2l[t] + S3l[0];
    }
    __syncthreads();
    for (int k = 16 + t; k < 512; k += BT) {
        const int c  = k >> 4;
        const int kp = k + (k >> 4);
        S1g[kp] = S1g[kp] + S2g[c - 1];
        S1l[kp] = S1l[kp] + S2l[c - 1];
    }
    __syncthreads();

    #pragma unroll
    for (int bi = 0; bi < 2; ++bi) {
        const int b = t + 256 * bi;
        float og = 0.f, ol = 0.f;
        if (b >= 1) {
            const int bp = (b - 1) + ((b - 1) >> 4);
            og = S1g[bp]; ol = S1l[bp];
        }
        float* __restrict__ cgp = &CG[TS * b];
        float* __restrict__ clp = &CL[TS * b];
        #pragma unroll
        for (int r = 0; r < 16; ++r) {
            cgp[r] = rg[bi][r] + og;
            clp[r] = rl[bi][r] + ol;
        }
    }
    __syncthreads();

    float* __restrict__ outr = out + (size_t)row * outW;
    for (int o = t; o < outW; o += BT) {
        const int j2 = o + wm1 - 1;
        const int i2 = TS * (j2 >> 4) + (j2 & 15);
        float cg1 = 0.f, cl1 = 0.f;
        if (o >= 1) {
            const int j1 = o - 1;
            const int i1 = TS * (j1 >> 4) + (j1 & 15);
            cg1 = CG[i1];
            cl1 = CL[i1];
        }
        const float a  = CG[i2] - cg1;
        const float bb = CL[i2] - cl1;
        float rs = 0.f;
        if (bb != 0.f) rs = a * __builtin_amdgcn_rcpf(bb);
        outr[o] = 1.f - __builtin_amdgcn_rcpf(1.f + rs);
    }
}

extern "C" void kernel_launch(void* const* d_in, const int* in_sizes, int n_in,
                              void* d_out, int out_size, void* d_ws, size_t ws_size,
                              hipStream_t stream) {
    const float* x   = (const float*)d_in[0];
    const int*   wsp = (const int*)d_in[1];
    float*       out = (float*)d_out;

    const int outW = out_size / ROWS;   // 8179
    const int wm1  = COLS - outW;       // == window_size - 1 (host-derived)
    dim3 grid(ROWS);                    // one block per row
    if (wm1 == 13) {
        rsi_reg_kernel<13><<<grid, dim3(BT8), 0, stream>>>(x, out, outW);
    } else {
        rsi_rwr_fallback<<<grid, dim3(BT), 0, stream>>>(x, wsp, out, outW);
    }
}